// Round 3
// baseline (2108.523 us; speedup 1.0000x reference)
//
#include <hip/hip_runtime.h>

typedef __attribute__((ext_vector_type(8))) short bf16x8;
typedef __attribute__((ext_vector_type(4))) float f32x4;
typedef unsigned short u16;

#define MFMA16(a, b, c) __builtin_amdgcn_mfma_f32_16x16x32_bf16(a, b, c, 0, 0, 0)

#define S_LEN 9216
#define CIN   512
#define KC    256
#define VC    256
#define CO    512
#define NB    2
#define KVTILES 144            // S_LEN / 64
#define KSPLIT  8
#define TILES_PER_SPLIT (KVTILES / KSPLIT)   // 18
#define NS (NB * S_LEN)

// RNE float -> bf16 bits
__device__ __forceinline__ u16 f2b(float f) {
    union { float f; unsigned u; } un; un.f = f;
    unsigned r = un.u + 0x7fffu + ((un.u >> 16) & 1u);
    return (u16)(r >> 16);
}
__device__ __forceinline__ float b2f(u16 b) {
    union { unsigned u; float f; } un; un.u = ((unsigned)b) << 16;
    return un.f;
}

// ---------------------------------------------------------------------------
// weight prep: fold BN into Wk, convert weights to bf16
// ---------------------------------------------------------------------------
__global__ __launch_bounds__(256)
void prep_weights(const float* __restrict__ Wk, const float* __restrict__ bk,
                  const float* __restrict__ gamma, const float* __restrict__ beta,
                  const float* __restrict__ rmean, const float* __restrict__ rvar,
                  const float* __restrict__ Wv, const float* __restrict__ Ww,
                  u16* __restrict__ Wkb, u16* __restrict__ Wvb,
                  u16* __restrict__ Wwb, float* __restrict__ bkf) {
    int i = blockIdx.x * 256 + threadIdx.x;
    if (i < KC * CIN) {
        int kc = i >> 9;  // /512
        float scale = gamma[kc] * rsqrtf(rvar[kc] + 1e-5f);
        Wkb[i] = f2b(Wk[i] * scale);
        Wvb[i] = f2b(Wv[i]);
    }
    if (i < CO * VC) Wwb[i] = f2b(Ww[i]);
    if (i < KC) {
        float scale = gamma[i] * rsqrtf(rvar[i] + 1e-5f);
        bkf[i] = bk[i] * scale + beta[i] - rmean[i] * scale;
    }
}

// ---------------------------------------------------------------------------
// transpose: x [N][C][S] f32  ->  xT [N][S][C] bf16
// ---------------------------------------------------------------------------
__global__ __launch_bounds__(256)
void transpose_x(const float* __restrict__ x, u16* __restrict__ xT) {
    __shared__ float t[32][33];
    const int s0 = blockIdx.x * 32, c0 = blockIdx.y * 32, n = blockIdx.z;
    const int tx = threadIdx.x, ty = threadIdx.y;
    const float* xb = x + (size_t)n * CIN * S_LEN;
#pragma unroll
    for (int i = 0; i < 4; ++i)
        t[ty + 8 * i][tx] = xb[(size_t)(c0 + ty + 8 * i) * S_LEN + s0 + tx];
    __syncthreads();
    u16* xo = xT + (size_t)n * S_LEN * CIN;
#pragma unroll
    for (int i = 0; i < 4; ++i)
        xo[(size_t)(s0 + ty + 8 * i) * CIN + c0 + tx] = f2b(t[tx][ty + 8 * i]);
}

// ---------------------------------------------------------------------------
// NT GEMM: D[i][j] = sum_k A[i][k] * B[j][k]   (A:[M][K], B:[N][K] bf16)
// EPI 0: +bias[col], relu, bf16 out   (k-projection)
// EPI 1: +bias[row], bf16 out         (v-projection)
// EPI 2: +bias[row], f32 out          (output projection)
// ---------------------------------------------------------------------------
template <int EPI>
__global__ __launch_bounds__(256)
void gemm_nt(const u16* __restrict__ A, const u16* __restrict__ B,
             const float* __restrict__ bias, void* __restrict__ Dout,
             int K, int ldd, size_t strideB, size_t strideD) {
    const int z = blockIdx.z;
    B += strideB * z;
    const int bm = blockIdx.x * 64;
    const int bn = blockIdx.y * 64;
    const int tid = threadIdx.x;
    const int wave = tid >> 6, lane = tid & 63, lr = lane & 15, lg = lane >> 4;
    const int wm = (wave >> 1) * 32, wn = (wave & 1) * 32;

    f32x4 acc[2][2];
#pragma unroll
    for (int i = 0; i < 2; ++i)
#pragma unroll
        for (int j = 0; j < 2; ++j) acc[i][j] = (f32x4){0.f, 0.f, 0.f, 0.f};

    for (int k0 = 0; k0 < K; k0 += 32) {
        bf16x8 af[2], bfr[2];
#pragma unroll
        for (int i = 0; i < 2; ++i)
            af[i] = *(const bf16x8*)(A + (size_t)(bm + wm + i * 16 + lr) * K + k0 + lg * 8);
#pragma unroll
        for (int j = 0; j < 2; ++j)
            bfr[j] = *(const bf16x8*)(B + (size_t)(bn + wn + j * 16 + lr) * K + k0 + lg * 8);
#pragma unroll
        for (int i = 0; i < 2; ++i)
#pragma unroll
            for (int j = 0; j < 2; ++j)
                acc[i][j] = MFMA16(af[i], bfr[j], acc[i][j]);
    }

#pragma unroll
    for (int i = 0; i < 2; ++i)
#pragma unroll
        for (int j = 0; j < 2; ++j)
#pragma unroll
            for (int r = 0; r < 4; ++r) {
                int row = bm + wm + i * 16 + lg * 4 + r;
                int col = bn + wn + j * 16 + lr;
                float val = acc[i][j][r] + (EPI == 0 ? bias[col] : bias[row]);
                if (EPI == 0) val = fmaxf(val, 0.f);
                if (EPI == 2)
                    ((float*)Dout)[strideD * z + (size_t)row * ldd + col] = val;
                else
                    ((u16*)Dout)[strideD * z + (size_t)row * ldd + col] = f2b(val);
            }
}

// ---------------------------------------------------------------------------
// flash attention, split-KV. Q,K from kT [N][S][256] bf16; V from v [N][256][S].
// Each block: one 64-row Q tile x one KV split (18 kv tiles of 64).
// No K/V LDS staging: K-frags and V-frags load directly from global (B-frag
// layout is 16B-contiguous per lane in both source layouts). Writes
// unnormalized partial acc (bf16) + per-row (m,l) (f32).
// ---------------------------------------------------------------------------
__global__ __launch_bounds__(256, 4)
void attn_kernel(const u16* __restrict__ kT, const u16* __restrict__ vmat,
                 u16* __restrict__ accP, float* __restrict__ ml) {
    const int qt = blockIdx.x;
    const int split = blockIdx.y;
    const int n = blockIdx.z;
    const int q0 = qt * 64;
    const u16* Kb = kT + (size_t)n * S_LEN * KC;
    const u16* Vb = vmat + (size_t)n * VC * S_LEN;

    const int tid = threadIdx.x;
    const int wave = tid >> 6;
    const int lane = tid & 63;
    const int lr = lane & 15;
    const int lg = lane >> 4;

    __shared__ __align__(16) u16 Plds[4][16 * 64];  // per-wave P, XOR-swizzled

    // Q A-frags (16 rows per wave, K=256)
    bf16x8 qf[8];
    {
        const u16* qrow = Kb + (size_t)(q0 + wave * 16 + lr) * KC + lg * 8;
#pragma unroll
        for (int ks = 0; ks < 8; ++ks) qf[ks] = *(const bf16x8*)(qrow + ks * 32);
    }

    f32x4 acc[16];
#pragma unroll
    for (int i = 0; i < 16; ++i) acc[i] = (f32x4){0.f, 0.f, 0.f, 0.f};
    float mrow[4] = {-1e30f, -1e30f, -1e30f, -1e30f};
    float lrow[4] = {0.f, 0.f, 0.f, 0.f};

    const int kv_lo = split * TILES_PER_SPLIT;
    for (int kv = kv_lo; kv < kv_lo + TILES_PER_SPLIT; ++kv) {
        const int s0 = kv * 64;

        // QK^T: 4 col-tiles of 16, K=256; K-frags direct from global
        f32x4 sfr[4];
#pragma unroll
        for (int ct = 0; ct < 4; ++ct) sfr[ct] = (f32x4){0.f, 0.f, 0.f, 0.f};
#pragma unroll
        for (int ks = 0; ks < 8; ++ks) {
#pragma unroll
            for (int ct = 0; ct < 4; ++ct) {
                bf16x8 kf = *(const bf16x8*)(Kb + (size_t)(s0 + ct * 16 + lr) * KC + ks * 32 + lg * 8);
                sfr[ct] = MFMA16(qf[ks], kf, sfr[ct]);
            }
        }

        // online softmax (rows = lg*4 + r, cols across lanes 0..15 of group)
#pragma unroll
        for (int r = 0; r < 4; ++r) {
            float v0 = sfr[0][r] * 0.0625f;
            float v1 = sfr[1][r] * 0.0625f;
            float v2 = sfr[2][r] * 0.0625f;
            float v3 = sfr[3][r] * 0.0625f;
            float mt = fmaxf(fmaxf(v0, v1), fmaxf(v2, v3));
#pragma unroll
            for (int off = 1; off < 16; off <<= 1) mt = fmaxf(mt, __shfl_xor(mt, off));
            float mnew = fmaxf(mrow[r], mt);
            float corr = __expf(mrow[r] - mnew);
            mrow[r] = mnew;
            float p0 = __expf(v0 - mnew);
            float p1 = __expf(v1 - mnew);
            float p2 = __expf(v2 - mnew);
            float p3 = __expf(v3 - mnew);
            float ps = p0 + p1 + p2 + p3;
#pragma unroll
            for (int off = 1; off < 16; off <<= 1) ps += __shfl_xor(ps, off);
            lrow[r] = lrow[r] * corr + ps;
#pragma unroll
            for (int ct = 0; ct < 16; ++ct) acc[ct][r] *= corr;
            int prow = lg * 4 + r;
            int swz = (prow & 7) << 4;
            char* pb = (char*)&Plds[wave][0];
            *(u16*)(pb + ((prow * 128 + (0 * 16 + lr) * 2) ^ swz)) = f2b(p0);
            *(u16*)(pb + ((prow * 128 + (1 * 16 + lr) * 2) ^ swz)) = f2b(p1);
            *(u16*)(pb + ((prow * 128 + (2 * 16 + lr) * 2) ^ swz)) = f2b(p2);
            *(u16*)(pb + ((prow * 128 + (3 * 16 + lr) * 2) ^ swz)) = f2b(p3);
        }

        // PV: ctx[16 x 256] += P[16 x 64] * V[64 x 256]; V-frags direct global
#pragma unroll
        for (int ks = 0; ks < 2; ++ks) {
            int pbyte = (lr * 128 + (ks * 32 + lg * 8) * 2) ^ ((lr & 7) << 4);
            bf16x8 pf = *(const bf16x8*)((char*)&Plds[wave][0] + pbyte);
#pragma unroll
            for (int ct = 0; ct < 16; ++ct) {
                bf16x8 vf = *(const bf16x8*)(Vb + (size_t)(ct * 16 + lr) * S_LEN + s0 + ks * 32 + lg * 8);
                acc[ct] = MFMA16(pf, vf, acc[ct]);
            }
        }
    }

    // epilogue: write unnormalized partial acc (bf16) + (m,l) per row
    const size_t pbase = (size_t)split * NS + (size_t)n * S_LEN + q0 + wave * 16;
#pragma unroll
    for (int r = 0; r < 4; ++r) {
        size_t rowidx = pbase + lg * 4 + r;
        size_t rowaddr = rowidx * VC;
#pragma unroll
        for (int ct = 0; ct < 16; ++ct)
            accP[rowaddr + ct * 16 + lr] = f2b(acc[ct][r]);
        if (lr == 0) {
            ml[rowidx * 2 + 0] = mrow[r];
            ml[rowidx * 2 + 1] = lrow[r];
        }
    }
}

// ---------------------------------------------------------------------------
// combine: merge KSPLIT partials -> ctx [N][S][VC] bf16
// ---------------------------------------------------------------------------
__global__ __launch_bounds__(256)
void combine_kernel(const u16* __restrict__ accP, const float* __restrict__ ml,
                    u16* __restrict__ ctx) {
    size_t idx = (size_t)blockIdx.x * 256 + threadIdx.x;  // NS * (VC/4) total
    int vc4 = (int)(idx & 63);
    size_t nrow = idx >> 6;
    float m[KSPLIT], l[KSPLIT];
    float M = -1e30f;
#pragma unroll
    for (int s = 0; s < KSPLIT; ++s) {
        m[s] = ml[((size_t)s * NS + nrow) * 2 + 0];
        l[s] = ml[((size_t)s * NS + nrow) * 2 + 1];
        M = fmaxf(M, m[s]);
    }
    float L = 0.f, w[KSPLIT];
#pragma unroll
    for (int s = 0; s < KSPLIT; ++s) {
        w[s] = __expf(m[s] - M);
        L += l[s] * w[s];
    }
    float invL = 1.0f / L;
    float o0 = 0.f, o1 = 0.f, o2 = 0.f, o3 = 0.f;
#pragma unroll
    for (int s = 0; s < KSPLIT; ++s) {
        ushort4 a = *(const ushort4*)(accP + ((size_t)s * NS + nrow) * VC + vc4 * 4);
        o0 += b2f(a.x) * w[s];
        o1 += b2f(a.y) * w[s];
        o2 += b2f(a.z) * w[s];
        o3 += b2f(a.w) * w[s];
    }
    ushort4 out;
    out.x = f2b(o0 * invL);
    out.y = f2b(o1 * invL);
    out.z = f2b(o2 * invL);
    out.w = f2b(o3 * invL);
    *(ushort4*)(ctx + nrow * VC + vc4 * 4) = out;
}

// ---------------------------------------------------------------------------
extern "C" void kernel_launch(void* const* d_in, const int* in_sizes, int n_in,
                              void* d_out, int out_size, void* d_ws, size_t ws_size,
                              hipStream_t stream) {
    const float* x     = (const float*)d_in[0];
    const float* Wk    = (const float*)d_in[1];
    const float* bk    = (const float*)d_in[2];
    const float* gamma = (const float*)d_in[3];
    const float* beta  = (const float*)d_in[4];
    const float* rmean = (const float*)d_in[5];
    const float* rvar  = (const float*)d_in[6];
    const float* Wv    = (const float*)d_in[7];
    const float* bv    = (const float*)d_in[8];
    const float* Ww    = (const float*)d_in[9];
    const float* bw    = (const float*)d_in[10];

    size_t off = 0;
    auto alloc = [&](size_t bytes) {
        void* p = (char*)d_ws + off;
        off += (bytes + 255) & ~(size_t)255;
        return p;
    };
    u16* xT   = (u16*)alloc((size_t)NB * S_LEN * CIN * 2);
    u16* kT   = (u16*)alloc((size_t)NB * S_LEN * KC * 2);
    u16* vm   = (u16*)alloc((size_t)NB * VC * S_LEN * 2);
    u16* ctx  = (u16*)alloc((size_t)NB * S_LEN * VC * 2);
    u16* Wkb  = (u16*)alloc((size_t)KC * CIN * 2);
    u16* Wvb  = (u16*)alloc((size_t)KC * CIN * 2);
    u16* Wwb  = (u16*)alloc((size_t)CO * VC * 2);
    float* bkf = (float*)alloc((size_t)KC * 4);
    u16* accP = (u16*)alloc((size_t)KSPLIT * NS * VC * 2);
    float* ml = (float*)alloc((size_t)KSPLIT * NS * 2 * 4);

    prep_weights<<<512, 256, 0, stream>>>(Wk, bk, gamma, beta, rmean, rvar, Wv, Ww,
                                          Wkb, Wvb, Wwb, bkf);
    transpose_x<<<dim3(S_LEN / 32, CIN / 32, NB), dim3(32, 8, 1), 0, stream>>>(x, xT);

    // kT[s][kc] = relu(bn(xT . Wk^T))  : M=N*S, N=KC, K=CIN
    gemm_nt<0><<<dim3(NB * S_LEN / 64, KC / 64, 1), 256, 0, stream>>>(
        xT, Wkb, bkf, kT, CIN, KC, 0, 0);
    // v[vc][s] = Wv . xT^T + bv        : M=VC, N=S, K=CIN, per batch
    gemm_nt<1><<<dim3(VC / 64, S_LEN / 64, NB), 256, 0, stream>>>(
        Wvb, xT, bv, vm, CIN, S_LEN, (size_t)S_LEN * CIN, (size_t)VC * S_LEN);

    attn_kernel<<<dim3(S_LEN / 64, KSPLIT, NB), 256, 0, stream>>>(kT, vm, accP, ml);
    combine_kernel<<<(NS * (VC / 4)) / 256, 256, 0, stream>>>(accP, ml, ctx);

    // out[co][s] = Ww . ctx^T + bw     : M=CO, N=S, K=VC, per batch, f32
    gemm_nt<2><<<dim3(CO / 64, S_LEN / 64, NB), 256, 0, stream>>>(
        Wwb, ctx, bw, d_out, VC, S_LEN, (size_t)S_LEN * VC, (size_t)CO * S_LEN);
}

// Round 4
// 892.882 us; speedup vs baseline: 2.3615x; 2.3615x over previous
//
#include <hip/hip_runtime.h>

typedef __attribute__((ext_vector_type(8))) short bf16x8;
typedef __attribute__((ext_vector_type(4))) float f32x4;
typedef unsigned short u16;

#define MFMA16(a, b, c) __builtin_amdgcn_mfma_f32_16x16x32_bf16(a, b, c, 0, 0, 0)

#define S_LEN 9216
#define CIN   512
#define KC    256
#define VC    256
#define CO    512
#define NB    2
#define KVTILES 144            // S_LEN / 64
#define KSPLIT  8
#define TILES_PER_SPLIT (KVTILES / KSPLIT)   // 18
#define NS (NB * S_LEN)

// RNE float -> bf16 bits
__device__ __forceinline__ u16 f2b(float f) {
    union { float f; unsigned u; } un; un.f = f;
    unsigned r = un.u + 0x7fffu + ((un.u >> 16) & 1u);
    return (u16)(r >> 16);
}
__device__ __forceinline__ float b2f(u16 b) {
    union { unsigned u; float f; } un; un.u = ((unsigned)b) << 16;
    return un.f;
}

// async global->LDS, 16B per lane; LDS dest = wave-uniform base + lane*16
__device__ __forceinline__ void gload_lds16(const u16* g, u16* l) {
    __builtin_amdgcn_global_load_lds(
        (const __attribute__((address_space(1))) unsigned*)g,
        (__attribute__((address_space(3))) unsigned*)l, 16, 0, 0);
}

// ---------------------------------------------------------------------------
// weight prep: fold BN into Wk, convert weights to bf16
// ---------------------------------------------------------------------------
__global__ __launch_bounds__(256)
void prep_weights(const float* __restrict__ Wk, const float* __restrict__ bk,
                  const float* __restrict__ gamma, const float* __restrict__ beta,
                  const float* __restrict__ rmean, const float* __restrict__ rvar,
                  const float* __restrict__ Wv, const float* __restrict__ Ww,
                  u16* __restrict__ Wkb, u16* __restrict__ Wvb,
                  u16* __restrict__ Wwb, float* __restrict__ bkf) {
    int i = blockIdx.x * 256 + threadIdx.x;
    if (i < KC * CIN) {
        int kc = i >> 9;  // /512
        float scale = gamma[kc] * rsqrtf(rvar[kc] + 1e-5f);
        Wkb[i] = f2b(Wk[i] * scale);
        Wvb[i] = f2b(Wv[i]);
    }
    if (i < CO * VC) Wwb[i] = f2b(Ww[i]);
    if (i < KC) {
        float scale = gamma[i] * rsqrtf(rvar[i] + 1e-5f);
        bkf[i] = bk[i] * scale + beta[i] - rmean[i] * scale;
    }
}

// ---------------------------------------------------------------------------
// transpose: x [N][C][S] f32  ->  xT [N][S][C] bf16
// ---------------------------------------------------------------------------
__global__ __launch_bounds__(256)
void transpose_x(const float* __restrict__ x, u16* __restrict__ xT) {
    __shared__ float t[32][33];
    const int s0 = blockIdx.x * 32, c0 = blockIdx.y * 32, n = blockIdx.z;
    const int tx = threadIdx.x, ty = threadIdx.y;
    const float* xb = x + (size_t)n * CIN * S_LEN;
#pragma unroll
    for (int i = 0; i < 4; ++i)
        t[ty + 8 * i][tx] = xb[(size_t)(c0 + ty + 8 * i) * S_LEN + s0 + tx];
    __syncthreads();
    u16* xo = xT + (size_t)n * S_LEN * CIN;
#pragma unroll
    for (int i = 0; i < 4; ++i)
        xo[(size_t)(s0 + ty + 8 * i) * CIN + c0 + tx] = f2b(t[tx][ty + 8 * i]);
}

// ---------------------------------------------------------------------------
// NT GEMM: D[i][j] = sum_k A[i][k] * B[j][k]   (A:[M][K], B:[N][K] bf16)
// EPI 0: +bias[col], relu, bf16 out   (k-projection)
// EPI 1: +bias[row], bf16 out         (v-projection)
// EPI 2: +bias[row], f32 out          (output projection)
// ---------------------------------------------------------------------------
template <int EPI>
__global__ __launch_bounds__(256)
void gemm_nt(const u16* __restrict__ A, const u16* __restrict__ B,
             const float* __restrict__ bias, void* __restrict__ Dout,
             int K, int ldd, size_t strideB, size_t strideD) {
    const int z = blockIdx.z;
    B += strideB * z;
    const int bm = blockIdx.x * 64;
    const int bn = blockIdx.y * 64;
    const int tid = threadIdx.x;
    const int wave = tid >> 6, lane = tid & 63, lr = lane & 15, lg = lane >> 4;
    const int wm = (wave >> 1) * 32, wn = (wave & 1) * 32;

    f32x4 acc[2][2];
#pragma unroll
    for (int i = 0; i < 2; ++i)
#pragma unroll
        for (int j = 0; j < 2; ++j) acc[i][j] = (f32x4){0.f, 0.f, 0.f, 0.f};

    for (int k0 = 0; k0 < K; k0 += 32) {
        bf16x8 af[2], bfr[2];
#pragma unroll
        for (int i = 0; i < 2; ++i)
            af[i] = *(const bf16x8*)(A + (size_t)(bm + wm + i * 16 + lr) * K + k0 + lg * 8);
#pragma unroll
        for (int j = 0; j < 2; ++j)
            bfr[j] = *(const bf16x8*)(B + (size_t)(bn + wn + j * 16 + lr) * K + k0 + lg * 8);
#pragma unroll
        for (int i = 0; i < 2; ++i)
#pragma unroll
            for (int j = 0; j < 2; ++j)
                acc[i][j] = MFMA16(af[i], bfr[j], acc[i][j]);
    }

#pragma unroll
    for (int i = 0; i < 2; ++i)
#pragma unroll
        for (int j = 0; j < 2; ++j)
#pragma unroll
            for (int r = 0; r < 4; ++r) {
                int row = bm + wm + i * 16 + lg * 4 + r;
                int col = bn + wn + j * 16 + lr;
                float val = acc[i][j][r] + (EPI == 0 ? bias[col] : bias[row]);
                if (EPI == 0) val = fmaxf(val, 0.f);
                if (EPI == 2)
                    ((float*)Dout)[strideD * z + (size_t)row * ldd + col] = val;
                else
                    ((u16*)Dout)[strideD * z + (size_t)row * ldd + col] = f2b(val);
            }
}

// ---------------------------------------------------------------------------
// flash attention, split-KV + LDS-staged K/V via global_load_lds.
// Q,K from kT [N][S][256] bf16; V from v [N][256][S] bf16.
// Each block: one 64-row Q tile x one KV split (18 kv tiles of 64).
// LDS dest is lane-linear; the XOR swizzle readers expect is applied by
// pre-swizzling the per-lane GLOBAL source address (involution, rule #21).
// Writes unnormalized partial acc (bf16) + per-row (m,l) (f32).
// ---------------------------------------------------------------------------
__global__ __launch_bounds__(256, 2)
void attn_kernel(const u16* __restrict__ kT, const u16* __restrict__ vmat,
                 u16* __restrict__ accP, float* __restrict__ ml) {
    const int qt = blockIdx.x;
    const int split = blockIdx.y;
    const int n = blockIdx.z;
    const int q0 = qt * 64;
    const u16* Kb = kT + (size_t)n * S_LEN * KC;
    const u16* Vb = vmat + (size_t)n * VC * S_LEN;

    const int tid = threadIdx.x;
    const int wave = tid >> 6;
    const int lane = tid & 63;
    const int lr = lane & 15;
    const int lg = lane >> 4;

    __shared__ __align__(16) u16 Klds[64 * 256];    // [kv_s][c], XOR-swizzled
    __shared__ __align__(16) u16 Vlds[256 * 64];    // [vc][kv_s], XOR-swizzled
    __shared__ __align__(16) u16 Plds[4][16 * 64];  // per-wave P, XOR-swizzled

    // Q A-frags (16 rows per wave, K=256)
    bf16x8 qf[8];
    {
        const u16* qrow = Kb + (size_t)(q0 + wave * 16 + lr) * KC + lg * 8;
#pragma unroll
        for (int ks = 0; ks < 8; ++ks) qf[ks] = *(const bf16x8*)(qrow + ks * 32);
    }

    f32x4 acc[16];
#pragma unroll
    for (int i = 0; i < 16; ++i) acc[i] = (f32x4){0.f, 0.f, 0.f, 0.f};
    float mrow[4] = {-1e30f, -1e30f, -1e30f, -1e30f};
    float lrow[4] = {0.f, 0.f, 0.f, 0.f};

    const int kv_lo = split * TILES_PER_SPLIT;
    for (int kv = kv_lo; kv < kv_lo + TILES_PER_SPLIT; ++kv) {
        const int s0 = kv * 64;
        __syncthreads();   // previous tile's compute done before overwrite
        // stage K tile (64 rows x 512B) and V tile (256 rows x 128B):
        // linear LDS dest, inverse-swizzled global source.
#pragma unroll
        for (int c = 0; c < 8; ++c) {
            {   // K: o in [0,65536)
                int o = ((c * 4 + wave) * 64 + lane) * 16;
                int row = o >> 9;
                int cu = (o & 511) ^ ((row & 7) << 4);
                gload_lds16(Kb + (size_t)(s0 + row) * KC + (cu >> 1),
                            &Klds[(c * 4 + wave) * 512]);
            }
            {   // V: o in [0,32768)
                int o = ((c * 4 + wave) * 64 + lane) * 16;
                int vc = o >> 7;
                int cu = (o & 127) ^ ((vc & 7) << 4);
                gload_lds16(Vb + (size_t)vc * S_LEN + s0 + (cu >> 1),
                            &Vlds[(c * 4 + wave) * 512]);
            }
        }
        __syncthreads();   // drains vmcnt before any wave reads LDS

        // QK^T: 4 col-tiles of 16, K=256
        f32x4 sfr[4];
#pragma unroll
        for (int ct = 0; ct < 4; ++ct) sfr[ct] = (f32x4){0.f, 0.f, 0.f, 0.f};
#pragma unroll
        for (int ks = 0; ks < 8; ++ks) {
#pragma unroll
            for (int ct = 0; ct < 4; ++ct) {
                int row = ct * 16 + lr;
                int byte = (row * 512 + (ks * 32 + lg * 8) * 2) ^ ((row & 7) << 4);
                bf16x8 kf = *(const bf16x8*)((char*)Klds + byte);
                sfr[ct] = MFMA16(qf[ks], kf, sfr[ct]);
            }
        }

        // online softmax (rows = lg*4 + r, cols across lanes 0..15 of group)
#pragma unroll
        for (int r = 0; r < 4; ++r) {
            float v0 = sfr[0][r] * 0.0625f;
            float v1 = sfr[1][r] * 0.0625f;
            float v2 = sfr[2][r] * 0.0625f;
            float v3 = sfr[3][r] * 0.0625f;
            float mt = fmaxf(fmaxf(v0, v1), fmaxf(v2, v3));
#pragma unroll
            for (int off = 1; off < 16; off <<= 1) mt = fmaxf(mt, __shfl_xor(mt, off));
            float mnew = fmaxf(mrow[r], mt);
            float corr = __expf(mrow[r] - mnew);
            mrow[r] = mnew;
            float p0 = __expf(v0 - mnew);
            float p1 = __expf(v1 - mnew);
            float p2 = __expf(v2 - mnew);
            float p3 = __expf(v3 - mnew);
            float ps = p0 + p1 + p2 + p3;
#pragma unroll
            for (int off = 1; off < 16; off <<= 1) ps += __shfl_xor(ps, off);
            lrow[r] = lrow[r] * corr + ps;
#pragma unroll
            for (int ct = 0; ct < 16; ++ct) acc[ct][r] *= corr;
            int prow = lg * 4 + r;
            int swz = (prow & 7) << 4;
            char* pb = (char*)&Plds[wave][0];
            *(u16*)(pb + ((prow * 128 + (0 * 16 + lr) * 2) ^ swz)) = f2b(p0);
            *(u16*)(pb + ((prow * 128 + (1 * 16 + lr) * 2) ^ swz)) = f2b(p1);
            *(u16*)(pb + ((prow * 128 + (2 * 16 + lr) * 2) ^ swz)) = f2b(p2);
            *(u16*)(pb + ((prow * 128 + (3 * 16 + lr) * 2) ^ swz)) = f2b(p3);
        }

        // PV: ctx[16 x 256] += P[16 x 64] * V[64 x 256]
#pragma unroll
        for (int ks = 0; ks < 2; ++ks) {
            int pbyte = (lr * 128 + (ks * 32 + lg * 8) * 2) ^ ((lr & 7) << 4);
            bf16x8 pf = *(const bf16x8*)((char*)&Plds[wave][0] + pbyte);
#pragma unroll
            for (int ct = 0; ct < 16; ++ct) {
                int vcq = ct * 16 + lr;
                int byte = (vcq * 128 + (ks * 32 + lg * 8) * 2) ^ ((vcq & 7) << 4);
                bf16x8 vf = *(const bf16x8*)((char*)Vlds + byte);
                acc[ct] = MFMA16(pf, vf, acc[ct]);
            }
        }
    }

    // epilogue: write unnormalized partial acc (bf16) + (m,l) per row
    const size_t pbase = (size_t)split * NS + (size_t)n * S_LEN + q0 + wave * 16;
#pragma unroll
    for (int r = 0; r < 4; ++r) {
        size_t rowidx = pbase + lg * 4 + r;
        size_t rowaddr = rowidx * VC;
#pragma unroll
        for (int ct = 0; ct < 16; ++ct)
            accP[rowaddr + ct * 16 + lr] = f2b(acc[ct][r]);
        if (lr == 0) {
            ml[rowidx * 2 + 0] = mrow[r];
            ml[rowidx * 2 + 1] = lrow[r];
        }
    }
}

// ---------------------------------------------------------------------------
// combine: merge KSPLIT partials -> ctx [N][S][VC] bf16
// ---------------------------------------------------------------------------
__global__ __launch_bounds__(256)
void combine_kernel(const u16* __restrict__ accP, const float* __restrict__ ml,
                    u16* __restrict__ ctx) {
    size_t idx = (size_t)blockIdx.x * 256 + threadIdx.x;  // NS * (VC/4) total
    int vc4 = (int)(idx & 63);
    size_t nrow = idx >> 6;
    float m[KSPLIT], l[KSPLIT];
    float M = -1e30f;
#pragma unroll
    for (int s = 0; s < KSPLIT; ++s) {
        m[s] = ml[((size_t)s * NS + nrow) * 2 + 0];
        l[s] = ml[((size_t)s * NS + nrow) * 2 + 1];
        M = fmaxf(M, m[s]);
    }
    float L = 0.f, w[KSPLIT];
#pragma unroll
    for (int s = 0; s < KSPLIT; ++s) {
        w[s] = __expf(m[s] - M);
        L += l[s] * w[s];
    }
    float invL = 1.0f / L;
    float o0 = 0.f, o1 = 0.f, o2 = 0.f, o3 = 0.f;
#pragma unroll
    for (int s = 0; s < KSPLIT; ++s) {
        ushort4 a = *(const ushort4*)(accP + ((size_t)s * NS + nrow) * VC + vc4 * 4);
        o0 += b2f(a.x) * w[s];
        o1 += b2f(a.y) * w[s];
        o2 += b2f(a.z) * w[s];
        o3 += b2f(a.w) * w[s];
    }
    ushort4 out;
    out.x = f2b(o0 * invL);
    out.y = f2b(o1 * invL);
    out.z = f2b(o2 * invL);
    out.w = f2b(o3 * invL);
    *(ushort4*)(ctx + nrow * VC + vc4 * 4) = out;
}

// ---------------------------------------------------------------------------
extern "C" void kernel_launch(void* const* d_in, const int* in_sizes, int n_in,
                              void* d_out, int out_size, void* d_ws, size_t ws_size,
                              hipStream_t stream) {
    const float* x     = (const float*)d_in[0];
    const float* Wk    = (const float*)d_in[1];
    const float* bk    = (const float*)d_in[2];
    const float* gamma = (const float*)d_in[3];
    const float* beta  = (const float*)d_in[4];
    const float* rmean = (const float*)d_in[5];
    const float* rvar  = (const float*)d_in[6];
    const float* Wv    = (const float*)d_in[7];
    const float* bv    = (const float*)d_in[8];
    const float* Ww    = (const float*)d_in[9];
    const float* bw    = (const float*)d_in[10];

    size_t off = 0;
    auto alloc = [&](size_t bytes) {
        void* p = (char*)d_ws + off;
        off += (bytes + 255) & ~(size_t)255;
        return p;
    };
    u16* xT   = (u16*)alloc((size_t)NB * S_LEN * CIN * 2);
    u16* kT   = (u16*)alloc((size_t)NB * S_LEN * KC * 2);
    u16* vm   = (u16*)alloc((size_t)NB * VC * S_LEN * 2);
    u16* ctx  = (u16*)alloc((size_t)NB * S_LEN * VC * 2);
    u16* Wkb  = (u16*)alloc((size_t)KC * CIN * 2);
    u16* Wvb  = (u16*)alloc((size_t)KC * CIN * 2);
    u16* Wwb  = (u16*)alloc((size_t)CO * VC * 2);
    float* bkf = (float*)alloc((size_t)KC * 4);
    u16* accP = (u16*)alloc((size_t)KSPLIT * NS * VC * 2);
    float* ml = (float*)alloc((size_t)KSPLIT * NS * 2 * 4);

    prep_weights<<<512, 256, 0, stream>>>(Wk, bk, gamma, beta, rmean, rvar, Wv, Ww,
                                          Wkb, Wvb, Wwb, bkf);
    transpose_x<<<dim3(S_LEN / 32, CIN / 32, NB), dim3(32, 8, 1), 0, stream>>>(x, xT);

    // kT[s][kc] = relu(bn(xT . Wk^T))  : M=N*S, N=KC, K=CIN
    gemm_nt<0><<<dim3(NB * S_LEN / 64, KC / 64, 1), 256, 0, stream>>>(
        xT, Wkb, bkf, kT, CIN, KC, 0, 0);
    // v[vc][s] = Wv . xT^T + bv        : M=VC, N=S, K=CIN, per batch
    gemm_nt<1><<<dim3(VC / 64, S_LEN / 64, NB), 256, 0, stream>>>(
        Wvb, xT, bv, vm, CIN, S_LEN, (size_t)S_LEN * CIN, (size_t)VC * S_LEN);

    attn_kernel<<<dim3(S_LEN / 64, KSPLIT, NB), 256, 0, stream>>>(kT, vm, accP, ml);
    combine_kernel<<<(NS * (VC / 4)) / 256, 256, 0, stream>>>(accP, ml, ctx);

    // out[co][s] = Ww . ctx^T + bw     : M=CO, N=S, K=VC, per batch, f32
    gemm_nt<2><<<dim3(CO / 64, S_LEN / 64, NB), 256, 0, stream>>>(
        Wwb, ctx, bw, d_out, VC, S_LEN, (size_t)S_LEN * VC, (size_t)CO * S_LEN);
}